// Round 3
// baseline (371.132 us; speedup 1.0000x reference)
//
#include <hip/hip_runtime.h>
#include <math.h>

// Problem constants (fixed by the reference setup_inputs)
#define BB 4
#define CC 256
#define HH 64
#define WW 64
#define PP 256
#define NPT 9
#define XSTR 296  // LDS x_off row stride in ushort (288 K + 8 pad; b128 conflict-free)

// Workspace layout (float element offsets)
#define WS_OFF   0ull        // [B][27][H][W]  = 442368
#define WS_Y     442368ull   // [B][P][H][W]   = 4194304
#define WS_SUM   4636672ull  // [256]
#define WS_SUMSQ 4636928ull  // [256]
#define WS_SCALE 4637184ull  // [256]
#define WS_SHIFT 4637440ull  // [256]
#define WS_WPMT  4637696ull  // [c][j][28] fp32 = 64512 (27 used + 1 pad)
#define WS_WF    4702208ull  // bf16 W frags [ksg72][ot16][quad4][ocin16][j8] = 589824 us
// total 4997120 floats = 20.0 MB

typedef __attribute__((ext_vector_type(8))) short bf16x8;
typedef __attribute__((ext_vector_type(4))) float f32x4;

static __device__ inline unsigned short f2bf(float f) {
  unsigned int u = __float_as_uint(f);
  unsigned int r = (u + 0x7FFFu + ((u >> 16) & 1u)) >> 16;
  return (unsigned short)r;
}

// ---------------------------------------------------------------------------
// K0: weight relayouts (re-done every call; ws re-poisoned before each launch).
// Fragment K-order: global K-step ksg = kb*9+ks covers conv-point k=ks,
// channels c = kb*32 + (quad*8+j)  [channel-minor within each 32-wide step].
// ---------------------------------------------------------------------------
__global__ void k_transpose(const float* __restrict__ w,
                            const float* __restrict__ w_p,
                            const float* __restrict__ w_m,
                            float* __restrict__ ws) {
  float* wPMt = ws + WS_WPMT;
  unsigned short* wfb = (unsigned short*)(ws + WS_WF);
  int idx = blockIdx.x * 256 + threadIdx.x;

  for (int e = idx; e < 256 * 256 * 9; e += gridDim.x * 256) {
    int j    = e & 7;
    int ocin = (e >> 3) & 15;
    int quad = (e >> 7) & 3;
    int ot   = (e >> 9) & 15;
    int ksg  = e >> 13;
    int kb = ksg / 9, ks = ksg - kb * 9;
    int c  = kb * 32 + quad * 8 + j;
    int oc = ot * 16 + ocin;
    wfb[e] = f2bf(w[((size_t)oc * CC + c) * 9 + ks]);
  }
  // offset+mask weights fused, padded to 28: [c][j][28]
  for (int i = idx; i < 256 * 9 * 28; i += gridDim.x * 256) {
    int oc = i % 28;
    int r  = i / 28;
    int j  = r % 9;
    int c  = r / 9;
    float v = 0.f;
    if (oc < 18)      v = w_p[((size_t)oc * CC + c) * 9 + j];
    else if (oc < 27) v = w_m[((size_t)(oc - 18) * CC + c) * 9 + j];
    wPMt[i] = v;
  }
}

// ---------------------------------------------------------------------------
// K1: fused offset (18ch) + mask (9ch, sigmoid) 3x3 conv, padding=1.
// grid = B*H*2 (512), block = 512 = 32 px x 16 channel-chunks (16 ch each).
// float4 weight loads ([c][j][28] padded layout), LDS reduce over chunks.
// ---------------------------------------------------------------------------
__global__ __launch_bounds__(512) void k_offmask(const float* __restrict__ x,
                                                 const float* __restrict__ b_p,
                                                 const float* __restrict__ b_m,
                                                 float* __restrict__ ws) {
  const float* wPMt = ws + WS_WPMT;
  float* offm = ws + WS_OFF;

  __shared__ float4 sAcc[7 * 16 * 32];  // [o4][chunk][px]

  int t = threadIdx.x;
  int px = t & 31;
  int chunk = t >> 5;
  int blk = blockIdx.x;
  int b = blk >> 7, h = (blk >> 1) & 63, side = blk & 1;
  int wcol = side * 32 + px;

  float4 acc4[7];
#pragma unroll
  for (int i = 0; i < 7; ++i) acc4[i] = (float4){0.f, 0.f, 0.f, 0.f};

  const float* xb = x + (size_t)b * CC * HH * WW;

  for (int ci = 0; ci < 16; ++ci) {
    int c = chunk * 16 + ci;
    const float* xp = xb + (size_t)c * HH * WW;
    float xv[9];
#pragma unroll
    for (int dh = -1; dh <= 1; ++dh) {
#pragma unroll
      for (int dw = -1; dw <= 1; ++dw) {
        int hh = h + dh, wv = wcol + dw;
        float v = 0.f;
        if ((unsigned)hh < 64u && (unsigned)wv < 64u) v = xp[hh * 64 + wv];
        xv[(dh + 1) * 3 + (dw + 1)] = v;
      }
    }
    const float4* wb4 = (const float4*)(wPMt + (size_t)c * 252);
#pragma unroll
    for (int j = 0; j < 9; ++j) {
      float xj = xv[j];
#pragma unroll
      for (int o4 = 0; o4 < 7; ++o4) {
        float4 w4 = wb4[j * 7 + o4];
        acc4[o4].x = fmaf(xj, w4.x, acc4[o4].x);
        acc4[o4].y = fmaf(xj, w4.y, acc4[o4].y);
        acc4[o4].z = fmaf(xj, w4.z, acc4[o4].z);
        acc4[o4].w = fmaf(xj, w4.w, acc4[o4].w);
      }
    }
  }

#pragma unroll
  for (int o4 = 0; o4 < 7; ++o4) sAcc[(o4 * 16 + chunk) * 32 + px] = acc4[o4];
  __syncthreads();

  for (int oi = t; oi < 28 * 32; oi += 512) {
    int oc = oi >> 5, pxo = oi & 31;
    if (oc >= 27) continue;
    int o4 = oc >> 2, comp = oc & 3;
    float s = 0.f;
#pragma unroll
    for (int ch = 0; ch < 16; ++ch) {
      float4 v = sAcc[(o4 * 16 + ch) * 32 + pxo];
      s += (comp == 0) ? v.x : (comp == 1) ? v.y : (comp == 2) ? v.z : v.w;
    }
    s += (oc < 18) ? b_p[oc] : b_m[oc - 18];
    if (oc >= 18) s = 1.f / (1.f + expf(-s));
    offm[(((size_t)b * 27 + oc) * 64 + h) * 64 + side * 32 + pxo] = s;
  }
}

// ---------------------------------------------------------------------------
// K2: deformable gather + bf16 MFMA contraction.
// grid = B*H*2 (512 blocks, 2/CU), block = 512 (8 waves), 32 px per block.
// Staging threads t<288 own one (px, k) pair; tap addrs/weights live in
// REGISTERS (no LDS round-trip, no phase-A barrier). Per 32-ch K-tile they
// loop channels in batches of 8 -> one b128 LDS write per batch.
// MFMA: wave = (pxt = wv&1, og = wv>>1), 4 oc-tiles each, acc 4 x f32x4.
// ---------------------------------------------------------------------------
__global__ __launch_bounds__(512) void k_deform(const float* __restrict__ x,
                                                float* __restrict__ ws) {
  const float* offm = ws + WS_OFF;
  const unsigned short* wfb = (const unsigned short*)(ws + WS_WF);
  float* y = ws + WS_Y;

  __shared__ __align__(16) unsigned short sXu[32 * XSTR];

  int t = threadIdx.x;
  int blk = blockIdx.x;
  int b = blk >> 7, h = (blk >> 1) & 63, side = blk & 1;

  // ---- per-thread tap setup (staging threads only) ----
  int a0 = 0, a1 = 0, a2 = 0, a3 = 0;
  float g0 = 0.f, g1 = 0.f, g2 = 0.f, g3 = 0.f;
  int spx = t & 31;        // staged pixel 0..31
  int skp = t >> 5;        // sampling point 0..8 (valid when t < 288)
  if (t < 288) {
    int wcol = side * 32 + spx;
    size_t base = (((size_t)b * 27) * 64 + h) * 64 + wcol;
    float offx = offm[base + (size_t)skp * 4096];
    float offy = offm[base + (size_t)(9 + skp) * 4096];
    float mk   = offm[base + (size_t)(18 + skp) * 4096];
    float pnx = (float)((skp / 3 - 1) * 6);
    float pny = (float)((skp % 3 - 1) * 6);
    float pxf = (float)(h + 1) + pnx + offx;
    float pyf = (float)(wcol + 1) + pny + offy;
    float fx = floorf(pxf), fy = floorf(pyf);
    float q0x = fminf(fmaxf(fx, 0.f), 75.f);
    float q1x = fminf(fmaxf(fx + 1.f, 0.f), 75.f);
    float q0y = fminf(fmaxf(fy, 0.f), 75.f);
    float q1y = fminf(fmaxf(fy + 1.f, 0.f), 75.f);
    float pxc = fminf(fmaxf(pxf, 0.f), 75.f);
    float pyc = fminf(fmaxf(pyf, 0.f), 75.f);
    float glt = (1.f + (q0x - pxc)) * (1.f + (q0y - pyc));
    float grb = (1.f - (q1x - pxc)) * (1.f - (q1y - pyc));
    float glb = (1.f + (q0x - pxc)) * (1.f - (q1y - pyc));
    float grt = (1.f - (q1x - pxc)) * (1.f + (q0y - pyc));
    int ix0 = (int)q0x - 6, ix1 = (int)q1x - 6;
    int iy0 = (int)q0y - 6, iy1 = (int)q1y - 6;
    bool v00 = (unsigned)ix0 < 64u && (unsigned)iy0 < 64u;
    bool v11 = (unsigned)ix1 < 64u && (unsigned)iy1 < 64u;
    bool v01 = (unsigned)ix0 < 64u && (unsigned)iy1 < 64u;
    bool v10 = (unsigned)ix1 < 64u && (unsigned)iy0 < 64u;
    a0 = v00 ? ix0 * 64 + iy0 : 0;
    a1 = v11 ? ix1 * 64 + iy1 : 0;
    a2 = v01 ? ix0 * 64 + iy1 : 0;
    a3 = v10 ? ix1 * 64 + iy0 : 0;
    g0 = v00 ? glt * mk : 0.f;
    g1 = v11 ? grb * mk : 0.f;
    g2 = v01 ? glb * mk : 0.f;
    g3 = v10 ? grt * mk : 0.f;
  }

  int lane = t & 63;
  int wv = __builtin_amdgcn_readfirstlane(t >> 6);
  int pxt = wv & 1;   // pixel tile 0..1
  int og  = wv >> 1;  // oc-tile group 0..3

  f32x4 acc[4];
#pragma unroll
  for (int i = 0; i < 4; ++i) acc[i] = (f32x4){0.f, 0.f, 0.f, 0.f};

  const float* xb = x + (size_t)b * CC * 4096;
  const unsigned short* bbase =
      &sXu[(pxt * 16 + (lane & 15)) * XSTR + (lane >> 4) * 8];

  for (int kb = 0; kb < 8; ++kb) {
    __syncthreads();  // sXu free (previous MFMA phase done)
    if (t < 288) {
      const float* xc = xb + (size_t)(kb * 32) * 4096;
      unsigned short* dst = &sXu[spx * XSTR + skp * 32];
#pragma unroll
      for (int cb = 0; cb < 4; ++cb) {
        const float* xq = xc + (size_t)(cb * 8) * 4096;
        float v[8];
#pragma unroll
        for (int i = 0; i < 8; ++i) {
          const float* xp = xq + (size_t)i * 4096;
          float val = g0 * xp[a0];
          val = fmaf(g1, xp[a1], val);
          val = fmaf(g2, xp[a2], val);
          val = fmaf(g3, xp[a3], val);
          v[i] = val;
        }
        unsigned int p0 = (unsigned int)f2bf(v[0]) | ((unsigned int)f2bf(v[1]) << 16);
        unsigned int p1 = (unsigned int)f2bf(v[2]) | ((unsigned int)f2bf(v[3]) << 16);
        unsigned int p2 = (unsigned int)f2bf(v[4]) | ((unsigned int)f2bf(v[5]) << 16);
        unsigned int p3 = (unsigned int)f2bf(v[6]) | ((unsigned int)f2bf(v[7]) << 16);
        uint4 pk = {p0, p1, p2, p3};
        *(uint4*)(dst + cb * 8) = pk;
      }
    }
    __syncthreads();
#pragma unroll
    for (int ks = 0; ks < 9; ++ks) {
      bf16x8 bf = *(const bf16x8*)(bbase + ks * 32);
      int ksg = kb * 9 + ks;
      const unsigned short* ap =
          wfb + (size_t)ksg * 8192 + (size_t)og * 2048 + lane * 8;
#pragma unroll
      for (int ot4 = 0; ot4 < 4; ++ot4) {
        bf16x8 af = *(const bf16x8*)(ap + ot4 * 512);
        acc[ot4] = __builtin_amdgcn_mfma_f32_16x16x32_bf16(af, bf, acc[ot4], 0, 0, 0);
      }
    }
  }

  // epilogue: D[oc][px]; oc = (og*4+ot)*16 + (lane>>4)*4 + r
  int pxl = pxt * 16 + (lane & 15);
  size_t ybase = (size_t)b * PP * 4096 + h * 64 + side * 32 + pxl;
#pragma unroll
  for (int ot4 = 0; ot4 < 4; ++ot4) {
#pragma unroll
    for (int r = 0; r < 4; ++r) {
      int oc = (og * 4 + ot4) * 16 + (lane >> 4) * 4 + r;
      y[ybase + (size_t)oc * 4096] = acc[ot4][r];
    }
  }
}

// ---------------------------------------------------------------------------
// K2b: per-channel sums over y (block = one channel).
// ---------------------------------------------------------------------------
__global__ __launch_bounds__(256) void k_ysum(float* __restrict__ ws) {
  const float* y = ws + WS_Y;
  __shared__ float sR[256], sR2[256];
  int oc = blockIdx.x, t = threadIdx.x;
  float s = 0.f, s2 = 0.f;
#pragma unroll
  for (int b = 0; b < 4; ++b) {
    const float4* yp = (const float4*)(y + ((size_t)b * 256 + oc) * 4096);
    for (int i = t; i < 1024; i += 256) {
      float4 v = yp[i];
      s += v.x + v.y + v.z + v.w;
      s2 = fmaf(v.x, v.x, s2);
      s2 = fmaf(v.y, v.y, s2);
      s2 = fmaf(v.z, v.z, s2);
      s2 = fmaf(v.w, v.w, s2);
    }
  }
  sR[t] = s;
  sR2[t] = s2;
  __syncthreads();
  for (int off = 128; off > 0; off >>= 1) {
    if (t < off) {
      sR[t] += sR[t + off];
      sR2[t] += sR2[t + off];
    }
    __syncthreads();
  }
  if (t == 0) {
    ws[WS_SUM + oc] = sR[0];
    ws[WS_SUMSQ + oc] = sR2[0];
  }
}

// ---------------------------------------------------------------------------
// K3: per-channel BN scale/shift.
// ---------------------------------------------------------------------------
__global__ void k_stats(float* __restrict__ ws, const float* __restrict__ gamma,
                        const float* __restrict__ beta) {
  int t = threadIdx.x;
  float s  = ws[WS_SUM + t];
  float s2 = ws[WS_SUMSQ + t];
  float mean = s * (1.f / 16384.f);
  float var  = fmaf(s2, 1.f / 16384.f, -mean * mean);
  float rstd = rsqrtf(var + 1e-5f);
  float sc = gamma[t] * rstd;
  ws[WS_SCALE + t] = sc;
  ws[WS_SHIFT + t] = fmaf(-mean, sc, beta[t]);
}

// ---------------------------------------------------------------------------
// K4: apply BN + ReLU, vectorized float4.
// ---------------------------------------------------------------------------
__global__ void k_bnrelu(const float* __restrict__ ws, float* __restrict__ out) {
  const float4* y4 = (const float4*)(ws + WS_Y);
  const float* scale = ws + WS_SCALE;
  const float* shift = ws + WS_SHIFT;
  float4* o4 = (float4*)out;
  const int n4 = BB * PP * (HH * WW / 4);
  for (int i = blockIdx.x * blockDim.x + threadIdx.x; i < n4;
       i += gridDim.x * blockDim.x) {
    int oc = (i >> 10) & 255;
    float sc = scale[oc], sh = shift[oc];
    float4 v = y4[i];
    float4 r;
    r.x = fmaxf(fmaf(v.x, sc, sh), 0.f);
    r.y = fmaxf(fmaf(v.y, sc, sh), 0.f);
    r.z = fmaxf(fmaf(v.z, sc, sh), 0.f);
    r.w = fmaxf(fmaf(v.w, sc, sh), 0.f);
    o4[i] = r;
  }
}

extern "C" void kernel_launch(void* const* d_in, const int* in_sizes, int n_in,
                              void* d_out, int out_size, void* d_ws,
                              size_t ws_size, hipStream_t stream) {
  const float* x     = (const float*)d_in[0];
  const float* w_p   = (const float*)d_in[1];
  const float* b_p   = (const float*)d_in[2];
  const float* w_m   = (const float*)d_in[3];
  const float* b_m   = (const float*)d_in[4];
  const float* w     = (const float*)d_in[5];
  const float* gamma = (const float*)d_in[6];
  const float* beta  = (const float*)d_in[7];
  float* ws  = (float*)d_ws;
  float* out = (float*)d_out;

  k_transpose<<<2304, 256, 0, stream>>>(w, w_p, w_m, ws);
  k_offmask<<<512, 512, 0, stream>>>(x, b_p, b_m, ws);
  k_deform<<<512, 512, 0, stream>>>(x, ws);
  k_ysum<<<256, 256, 0, stream>>>(ws);
  k_stats<<<1, 256, 0, stream>>>(ws, gamma, beta);
  k_bnrelu<<<2048, 256, 0, stream>>>(ws, out);
}

// Round 4
// 267.806 us; speedup vs baseline: 1.3858x; 1.3858x over previous
//
#include <hip/hip_runtime.h>
#include <math.h>

// Problem constants (fixed by the reference setup_inputs)
#define CC 256
#define PP 256
#define XSTR 296  // LDS x_off row stride in ushort (288 K + 8 pad)

// Workspace layout (float element offsets)
#define WS_OFF   0ull        // [B][27][H][W]        = 442368
#define WS_Y     442368ull   // [B][P][H][W]         = 4194304
#define WS_SUM   4636672ull  // [256]
#define WS_SUMSQ 4636928ull  // [256]
#define WS_SCALE 4637184ull  // [256]
#define WS_SHIFT 4637440ull  // [256]
#define WS_XT    4637696ull  // NHWC x: [B][H][W][C] = 4194304 floats
#define WS_WF    8832000ull  // main W frags [ksg72][ot16][quad4][ocin16][j8] = 589824 us
#define WS_WPMF  9126912ull  // offs/mask W frags [ksg72][ot2][quad4][ocin16][j8] = 73728 us
// end: 9163776 floats = 36.7 MB

typedef __attribute__((ext_vector_type(8))) short bf16x8;
typedef __attribute__((ext_vector_type(4))) float f32x4;

static __device__ inline unsigned short f2bf(float f) {
  unsigned int u = __float_as_uint(f);
  unsigned int r = (u + 0x7FFFu + ((u >> 16) & 1u)) >> 16;
  return (unsigned short)r;
}

// ---------------------------------------------------------------------------
// K0: x NCHW -> NHWC transpose (blocks 0..1023) + weight fragment relayouts
// (blocks 1024..1663) + zero BN accumulators. Re-done every call.
// ---------------------------------------------------------------------------
__global__ __launch_bounds__(256) void k_prep(const float* __restrict__ x,
                                              const float* __restrict__ w,
                                              const float* __restrict__ w_p,
                                              const float* __restrict__ w_m,
                                              float* __restrict__ ws) {
  int blk = blockIdx.x, t = threadIdx.x;
  if (blk < 1024) {
    // transpose one (b, h, 64-channel) tile: x[b][c][h][w] -> xT[b][h][w][c]
    __shared__ float sT[64][65];
    int b = blk >> 8, h = (blk >> 2) & 63, c0 = (blk & 3) * 64;
    const float* xs = x + ((size_t)(b * 256 + c0) * 64 + h) * 64;
    int cl = t >> 6, wl = t & 63;
#pragma unroll
    for (int it = 0; it < 16; ++it) {
      int c = cl + it * 4;
      sT[c][wl] = xs[(size_t)c * 4096 + wl];
    }
    __syncthreads();
    float* xt = ws + WS_XT + ((size_t)b * 64 + h) * 16384 + c0;
    int c2 = t & 63, w2l = t >> 6;
#pragma unroll
    for (int it = 0; it < 16; ++it) {
      int w2 = w2l + it * 4;
      xt[(size_t)w2 * 256 + c2] = sT[c2][w2];
    }
  } else {
    int gid = (blk - 1024) * 256 + t;
    if (blk == 1024 && t < 512) ws[WS_SUM + t] = 0.f;  // SUM + SUMSQ
    // main weight frags: K-step ksg=kb*9+ks covers c = kb*32+quad*8+j, point ks
    unsigned short* wfb = (unsigned short*)(ws + WS_WF);
    for (int e = gid; e < 589824; e += 163840) {
      int j = e & 7, ocin = (e >> 3) & 15, quad = (e >> 7) & 3;
      int ot = (e >> 9) & 15, ksg = e >> 13;
      int kb = ksg / 9, ks = ksg - kb * 9;
      int c = kb * 32 + quad * 8 + j;
      int oc = ot * 16 + ocin;
      wfb[e] = f2bf(w[((size_t)oc * CC + c) * 9 + ks]);
    }
    // offset+mask weight frags (27 oc padded to 32), same K-order
    unsigned short* wpmf = (unsigned short*)(ws + WS_WPMF);
    for (int e = gid; e < 73728; e += 163840) {
      int j = e & 7, ocin = (e >> 3) & 15, quad = (e >> 7) & 3;
      int ot = (e >> 9) & 1, ksg = e >> 10;
      int kb = ksg / 9, ks = ksg - kb * 9;
      int c = kb * 32 + quad * 8 + j;
      int oc = ot * 16 + ocin;
      float v = 0.f;
      if (oc < 18)      v = w_p[((size_t)oc * CC + c) * 9 + ks];
      else if (oc < 27) v = w_m[((size_t)(oc - 18) * CC + c) * 9 + ks];
      wpmf[e] = f2bf(v);
    }
  }
}

// ---------------------------------------------------------------------------
// K1: fused offset(18) + mask(9, sigmoid) 3x3 conv as im2col bf16 MFMA GEMM.
// grid = 256 (XCD-swizzled b,h), block = 1024 (16 waves), 64 px per block.
// M=32 (27 used), K split across wave-halves (ks 0-4 / 5-8), LDS reduce.
// ---------------------------------------------------------------------------
__global__ __launch_bounds__(1024) void k_offmask(const float* __restrict__ b_p,
                                                  const float* __restrict__ b_m,
                                                  float* __restrict__ ws) {
  const float* xT = ws + WS_XT;
  const unsigned short* wpmf = (const unsigned short*)(ws + WS_WPMF);
  float* offm = ws + WS_OFF;
  __shared__ int sTO[576];
  __shared__ __align__(16) unsigned short sXo[64 * XSTR];

  int t = threadIdx.x, blk = blockIdx.x;
  int xcd = blk & 7, ii = blk >> 3;
  int b = xcd >> 1, h = (xcd & 1) * 32 + ii;

  if (t < 576) {  // conv tap addresses, -1 = zero-pad
    int jj = t / 64, px = t & 63;
    int row = h + jj / 3 - 1, col = px + jj % 3 - 1;
    sTO[t] = ((unsigned)row < 64u && (unsigned)col < 64u) ? row * 64 + col : -1;
  }
  __syncthreads();

  int lane = t & 63, wv = __builtin_amdgcn_readfirstlane(t >> 6);
  int pxt = wv & 3, ot = (wv >> 2) & 1, kh = wv >> 3;
  f32x4 acc = {0.f, 0.f, 0.f, 0.f};
  const float* xbT = xT + (size_t)b * 1048576;
  int cl = lane & 31;

  for (int kb = 0; kb < 8; ++kb) {
    __syncthreads();
    for (int u = wv * 18; u < wv * 18 + 18; ++u) {
      int j = u / 32, pp = u % 32;
      int px = pp * 2 + (lane >> 5);
      int a = sTO[j * 64 + px];
      float val = 0.f;
      if (a >= 0) val = xbT[a * 256 + kb * 32 + cl];
      sXo[px * XSTR + j * 32 + cl] = f2bf(val);
    }
    __syncthreads();
#pragma unroll
    for (int ks = 0; ks < 9; ++ks) {
      if ((int)(ks >= 5) == kh) {
        int ksg = kb * 9 + ks;
        bf16x8 bf = *(const bf16x8*)&sXo[(pxt * 16 + (lane & 15)) * XSTR +
                                         (lane >> 4) * 8 + ks * 32];
        bf16x8 af = *(const bf16x8*)(wpmf + (size_t)ksg * 1024 + ot * 512 + lane * 8);
        acc = __builtin_amdgcn_mfma_f32_16x16x32_bf16(af, bf, acc, 0, 0, 0);
      }
    }
  }
  __syncthreads();
  float* sR = (float*)sXo;
  if (kh == 1) {
    int base = (pxt * 2 + ot) * 256 + lane * 4;
#pragma unroll
    for (int r = 0; r < 4; ++r) sR[base + r] = acc[r];
  }
  __syncthreads();
  if (kh == 0) {
    int base = (pxt * 2 + ot) * 256 + lane * 4;
    int px = pxt * 16 + (lane & 15);
#pragma unroll
    for (int r = 0; r < 4; ++r) {
      int oc = ot * 16 + (lane >> 4) * 4 + r;
      if (oc < 27) {
        float v = acc[r] + sR[base + r];
        v += (oc < 18) ? b_p[oc] : b_m[oc - 18];
        if (oc >= 18) v = 1.f / (1.f + expf(-v));
        offm[((size_t)b * 27 + oc) * 4096 + h * 64 + px] = v;
      }
    }
  }
}

// ---------------------------------------------------------------------------
// K2: deformable gather (NHWC coalesced) + bf16 MFMA + BN partial sums.
// grid = 256 (XCD-swizzled), block = 1024 (16 waves), 64 px (one row).
// Phase A: taps packed per (px,k) into 16B (4 u16 addrs + 4 bf16 weights).
// Per 32-ch K-tile: units (px-pair, k) do 4 coalesced 128B tap loads each.
// ---------------------------------------------------------------------------
__global__ __launch_bounds__(1024) void k_deform(float* __restrict__ ws) {
  const float* offm = ws + WS_OFF;
  const float* xT = ws + WS_XT;
  const unsigned short* wfb = (const unsigned short*)(ws + WS_WF);
  float* y = ws + WS_Y;

  __shared__ __align__(16) uint4 sPK[576];
  __shared__ __align__(16) unsigned short sXu[64 * XSTR];

  int t = threadIdx.x, blk = blockIdx.x;
  int xcd = blk & 7, ii = blk >> 3;
  int b = xcd >> 1, h = (xcd & 1) * 32 + ii;

  if (t < 576) {
    int k = t / 64, w = t & 63;
    size_t base = ((size_t)b * 27) * 4096 + h * 64 + w;
    float offx = offm[base + (size_t)k * 4096];
    float offy = offm[base + (size_t)(9 + k) * 4096];
    float mk   = offm[base + (size_t)(18 + k) * 4096];
    float pnx = (float)((k / 3 - 1) * 6);
    float pny = (float)((k % 3 - 1) * 6);
    float pxf = (float)(h + 1) + pnx + offx;
    float pyf = (float)(w + 1) + pny + offy;
    float fx = floorf(pxf), fy = floorf(pyf);
    float q0x = fminf(fmaxf(fx, 0.f), 75.f);
    float q1x = fminf(fmaxf(fx + 1.f, 0.f), 75.f);
    float q0y = fminf(fmaxf(fy, 0.f), 75.f);
    float q1y = fminf(fmaxf(fy + 1.f, 0.f), 75.f);
    float pxc = fminf(fmaxf(pxf, 0.f), 75.f);
    float pyc = fminf(fmaxf(pyf, 0.f), 75.f);
    float glt = (1.f + (q0x - pxc)) * (1.f + (q0y - pyc));
    float grb = (1.f - (q1x - pxc)) * (1.f - (q1y - pyc));
    float glb = (1.f + (q0x - pxc)) * (1.f - (q1y - pyc));
    float grt = (1.f - (q1x - pxc)) * (1.f + (q0y - pyc));
    int ix0 = (int)q0x - 6, ix1 = (int)q1x - 6;
    int iy0 = (int)q0y - 6, iy1 = (int)q1y - 6;
    bool v00 = (unsigned)ix0 < 64u && (unsigned)iy0 < 64u;
    bool v11 = (unsigned)ix1 < 64u && (unsigned)iy1 < 64u;
    bool v01 = (unsigned)ix0 < 64u && (unsigned)iy1 < 64u;
    bool v10 = (unsigned)ix1 < 64u && (unsigned)iy0 < 64u;
    unsigned a0 = v00 ? (unsigned)(ix0 * 64 + iy0) : 0u;
    unsigned a1 = v11 ? (unsigned)(ix1 * 64 + iy1) : 0u;
    unsigned a2 = v01 ? (unsigned)(ix0 * 64 + iy1) : 0u;
    unsigned a3 = v10 ? (unsigned)(ix1 * 64 + iy0) : 0u;
    float g0 = v00 ? glt * mk : 0.f;
    float g1 = v11 ? grb * mk : 0.f;
    float g2 = v01 ? glb * mk : 0.f;
    float g3 = v10 ? grt * mk : 0.f;
    uint4 pk;
    pk.x = a0 | (a1 << 16);
    pk.y = a2 | (a3 << 16);
    pk.z = (unsigned)f2bf(g0) | ((unsigned)f2bf(g1) << 16);
    pk.w = (unsigned)f2bf(g2) | ((unsigned)f2bf(g3) << 16);
    sPK[t] = pk;
  }
  __syncthreads();

  int lane = t & 63, wv = __builtin_amdgcn_readfirstlane(t >> 6);
  int pxt = wv & 3, og = wv >> 2;
  f32x4 acc[4];
#pragma unroll
  for (int i = 0; i < 4; ++i) acc[i] = (f32x4){0.f, 0.f, 0.f, 0.f};

  const float* xbT = xT + (size_t)b * 1048576;
  int cl = lane & 31;
  const unsigned short* bbase =
      &sXu[(pxt * 16 + (lane & 15)) * XSTR + (lane >> 4) * 8];

  for (int kb = 0; kb < 8; ++kb) {
    __syncthreads();
    const float* xc = xbT + kb * 32 + cl;
    for (int u = wv * 18; u < wv * 18 + 18; ++u) {
      int k = u / 32, pp = u % 32;
      int px = pp * 2 + (lane >> 5);
      uint4 pk = sPK[k * 64 + px];
      float v0 = xc[(int)(pk.x & 0xFFFFu) * 256];
      float v1 = xc[(int)(pk.x >> 16) * 256];
      float v2 = xc[(int)(pk.y & 0xFFFFu) * 256];
      float v3 = xc[(int)(pk.y >> 16) * 256];
      float g0 = __uint_as_float((pk.z & 0xFFFFu) << 16);
      float g1 = __uint_as_float(pk.z & 0xFFFF0000u);
      float g2 = __uint_as_float((pk.w & 0xFFFFu) << 16);
      float g3 = __uint_as_float(pk.w & 0xFFFF0000u);
      float val = g0 * v0;
      val = fmaf(g1, v1, val);
      val = fmaf(g2, v2, val);
      val = fmaf(g3, v3, val);
      sXu[px * XSTR + k * 32 + cl] = f2bf(val);
    }
    __syncthreads();
#pragma unroll
    for (int ks = 0; ks < 9; ++ks) {
      bf16x8 bf = *(const bf16x8*)(bbase + ks * 32);
      int ksg = kb * 9 + ks;
      const unsigned short* ap =
          wfb + (size_t)ksg * 8192 + (size_t)og * 2048 + lane * 8;
#pragma unroll
      for (int ot4 = 0; ot4 < 4; ++ot4) {
        bf16x8 af = *(const bf16x8*)(ap + ot4 * 512);
        acc[ot4] = __builtin_amdgcn_mfma_f32_16x16x32_bf16(af, bf, acc[ot4], 0, 0, 0);
      }
    }
  }

  // epilogue: y stores + per-channel partial sums (16-lane xor-reduce)
  __syncthreads();  // sPK / sXu dead; reuse sPK as reduce buffer
  float* sP = (float*)sPK;       // [4 pxt][256 oc] sums
  float* sP2 = sP + 1024;        // [4 pxt][256 oc] sumsq (fits in 2304 floats)
  int px = pxt * 16 + (lane & 15);
  size_t ybase = (size_t)b * PP * 4096 + h * 64 + px;
#pragma unroll
  for (int ot4 = 0; ot4 < 4; ++ot4) {
#pragma unroll
    for (int r = 0; r < 4; ++r) {
      float v = acc[ot4][r];
      int oc = (og * 4 + ot4) * 16 + (lane >> 4) * 4 + r;
      y[ybase + (size_t)oc * 4096] = v;
      float s = v, s2 = v * v;
      s += __shfl_xor(s, 1);  s2 += __shfl_xor(s2, 1);
      s += __shfl_xor(s, 2);  s2 += __shfl_xor(s2, 2);
      s += __shfl_xor(s, 4);  s2 += __shfl_xor(s2, 4);
      s += __shfl_xor(s, 8);  s2 += __shfl_xor(s2, 8);
      if ((lane & 15) == 0) {
        sP[pxt * 256 + oc] = s;
        sP2[pxt * 256 + oc] = s2;
      }
    }
  }
  __syncthreads();
  if (t < 256) {
    float s = sP[t] + sP[256 + t] + sP[512 + t] + sP[768 + t];
    float s2 = sP2[t] + sP2[256 + t] + sP2[512 + t] + sP2[768 + t];
    atomicAdd(&ws[WS_SUM + t], s);
    atomicAdd(&ws[WS_SUMSQ + t], s2);
  }
}

// ---------------------------------------------------------------------------
// K3: per-channel BN scale/shift.
// ---------------------------------------------------------------------------
__global__ void k_stats(float* __restrict__ ws, const float* __restrict__ gamma,
                        const float* __restrict__ beta) {
  int t = threadIdx.x;
  float s  = ws[WS_SUM + t];
  float s2 = ws[WS_SUMSQ + t];
  float mean = s * (1.f / 16384.f);
  float var  = fmaf(s2, 1.f / 16384.f, -mean * mean);
  float rstd = rsqrtf(var + 1e-5f);
  float sc = gamma[t] * rstd;
  ws[WS_SCALE + t] = sc;
  ws[WS_SHIFT + t] = fmaf(-mean, sc, beta[t]);
}

// ---------------------------------------------------------------------------
// K4: apply BN + ReLU, vectorized float4.
// ---------------------------------------------------------------------------
__global__ void k_bnrelu(const float* __restrict__ ws, float* __restrict__ out) {
  const float4* y4 = (const float4*)(ws + WS_Y);
  const float* scale = ws + WS_SCALE;
  const float* shift = ws + WS_SHIFT;
  float4* o4 = (float4*)out;
  const int n4 = 4 * PP * 1024;
  for (int i = blockIdx.x * blockDim.x + threadIdx.x; i < n4;
       i += gridDim.x * blockDim.x) {
    int oc = (i >> 10) & 255;
    float sc = scale[oc], sh = shift[oc];
    float4 v = y4[i];
    float4 r;
    r.x = fmaxf(fmaf(v.x, sc, sh), 0.f);
    r.y = fmaxf(fmaf(v.y, sc, sh), 0.f);
    r.z = fmaxf(fmaf(v.z, sc, sh), 0.f);
    r.w = fmaxf(fmaf(v.w, sc, sh), 0.f);
    o4[i] = r;
  }
}

extern "C" void kernel_launch(void* const* d_in, const int* in_sizes, int n_in,
                              void* d_out, int out_size, void* d_ws,
                              size_t ws_size, hipStream_t stream) {
  const float* x     = (const float*)d_in[0];
  const float* w_p   = (const float*)d_in[1];
  const float* b_p   = (const float*)d_in[2];
  const float* w_m   = (const float*)d_in[3];
  const float* b_m   = (const float*)d_in[4];
  const float* w     = (const float*)d_in[5];
  const float* gamma = (const float*)d_in[6];
  const float* beta  = (const float*)d_in[7];
  float* ws  = (float*)d_ws;
  float* out = (float*)d_out;

  k_prep<<<1664, 256, 0, stream>>>(x, w, w_p, w_m, ws);
  k_offmask<<<256, 1024, 0, stream>>>(b_p, b_m, ws);
  k_deform<<<256, 1024, 0, stream>>>(ws);
  k_stats<<<1, 256, 0, stream>>>(ws, gamma, beta);
  k_bnrelu<<<2048, 256, 0, stream>>>(ws, out);
}

// Round 5
// 169.663 us; speedup vs baseline: 2.1875x; 1.5785x over previous
//
#include <hip/hip_runtime.h>
#include <math.h>

// Problem constants (fixed by the reference setup_inputs)
#define CC 256
#define PP 256
#define XSTR 296  // LDS x_off row stride in ushort (288 K + 8 pad)

// Workspace layout (float element offsets)
#define WS_OFF   0ull        // [B][27][H][W]        = 442368
#define WS_Y     442368ull   // [B][P][H][W]         = 4194304
#define WS_SUM   4636672ull  // [256]
#define WS_SUMSQ 4636928ull  // [256]
#define WS_SCALE 4637184ull  // [256]
#define WS_SHIFT 4637440ull  // [256]
#define WS_XT    4637696ull  // NHWC x: [B][H][W][C] = 4194304 floats
#define WS_WF    8832000ull  // main W frags [ksg72][ot16][quad4][ocin16][j8] = 589824 us
#define WS_WPMF  9126912ull  // offs/mask W frags [ksg72][ot2][quad4][ocin16][j8] = 73728 us
// end: 9163776 floats = 36.7 MB

typedef __attribute__((ext_vector_type(8))) short bf16x8;
typedef __attribute__((ext_vector_type(4))) float f32x4;

static __device__ inline unsigned short f2bf(float f) {
  unsigned int u = __float_as_uint(f);
  unsigned int r = (u + 0x7FFFu + ((u >> 16) & 1u)) >> 16;
  return (unsigned short)r;
}

// ---------------------------------------------------------------------------
// K0: x NCHW -> NHWC transpose (blocks 0..1023) + weight fragment relayouts
// (blocks 1024..1663) + zero BN accumulators. Re-done every call.
// ---------------------------------------------------------------------------
__global__ __launch_bounds__(256) void k_prep(const float* __restrict__ x,
                                              const float* __restrict__ w,
                                              const float* __restrict__ w_p,
                                              const float* __restrict__ w_m,
                                              float* __restrict__ ws) {
  int blk = blockIdx.x, t = threadIdx.x;
  if (blk < 1024) {
    __shared__ float sT[64][65];
    int b = blk >> 8, h = (blk >> 2) & 63, c0 = (blk & 3) * 64;
    const float* xs = x + ((size_t)(b * 256 + c0) * 64 + h) * 64;
    int cl = t >> 6, wl = t & 63;
#pragma unroll
    for (int it = 0; it < 16; ++it) {
      int c = cl + it * 4;
      sT[c][wl] = xs[(size_t)c * 4096 + wl];
    }
    __syncthreads();
    float* xt = ws + WS_XT + ((size_t)b * 64 + h) * 16384 + c0;
    int c2 = t & 63, w2l = t >> 6;
#pragma unroll
    for (int it = 0; it < 16; ++it) {
      int w2 = w2l + it * 4;
      xt[(size_t)w2 * 256 + c2] = sT[c2][w2];
    }
  } else {
    int gid = (blk - 1024) * 256 + t;
    if (blk == 1024 && t < 512) ws[WS_SUM + t] = 0.f;  // SUM + SUMSQ
    unsigned short* wfb = (unsigned short*)(ws + WS_WF);
    for (int e = gid; e < 589824; e += 163840) {
      int j = e & 7, ocin = (e >> 3) & 15, quad = (e >> 7) & 3;
      int ot = (e >> 9) & 15, ksg = e >> 13;
      int kb = ksg / 9, ks = ksg - kb * 9;
      int c = kb * 32 + quad * 8 + j;
      int oc = ot * 16 + ocin;
      wfb[e] = f2bf(w[((size_t)oc * CC + c) * 9 + ks]);
    }
    unsigned short* wpmf = (unsigned short*)(ws + WS_WPMF);
    for (int e = gid; e < 73728; e += 163840) {
      int j = e & 7, ocin = (e >> 3) & 15, quad = (e >> 7) & 3;
      int ot = (e >> 9) & 1, ksg = e >> 10;
      int kb = ksg / 9, ks = ksg - kb * 9;
      int c = kb * 32 + quad * 8 + j;
      int oc = ot * 16 + ocin;
      float v = 0.f;
      if (oc < 18)      v = w_p[((size_t)oc * CC + c) * 9 + ks];
      else if (oc < 27) v = w_m[((size_t)(oc - 18) * CC + c) * 9 + ks];
      wpmf[e] = f2bf(v);
    }
  }
}

// ---------------------------------------------------------------------------
// K1: fused offset(18) + mask(9, sigmoid) 3x3 conv as im2col bf16 MFMA GEMM.
// grid = 512 (XCD-swizzled), block = 512 (8 waves), 32 px per block.
// Staging: float4 im2col copy; MFMA M=32 (27 used), K split over wave-halves.
// ---------------------------------------------------------------------------
__global__ __launch_bounds__(512, 4) void k_offmask(const float* __restrict__ b_p,
                                                    const float* __restrict__ b_m,
                                                    float* __restrict__ ws) {
  const float* xT = ws + WS_XT;
  const unsigned short* wpmf = (const unsigned short*)(ws + WS_WPMF);
  float* offm = ws + WS_OFF;
  __shared__ __align__(16) unsigned short sXo[32 * XSTR];

  int t = threadIdx.x, blk = blockIdx.x;
  int xcd = blk & 7, ii = blk >> 3;
  int b = xcd >> 1, h = (xcd & 1) * 32 + (ii >> 1), side = ii & 1;

  int lane = t & 63, wv = __builtin_amdgcn_readfirstlane(t >> 6);
  int pxt = wv & 1, ot = (wv >> 1) & 1, kh = wv >> 2;
  f32x4 acc = {0.f, 0.f, 0.f, 0.f};
  const float4* xb4 = (const float4*)(xT + (size_t)b * 1048576);
  const unsigned short* bb =
      &sXo[(pxt * 16 + (lane & 15)) * XSTR + (lane >> 4) * 8];
  int uq = t >> 3, q = t & 7;

  for (int kb = 0; kb < 8; ++kb) {
    __syncthreads();
#pragma unroll
    for (int r = 0; r < 5; ++r) {
      int u = r * 64 + uq;
      if (u < 288) {
        int j = u >> 5, px = u & 31;
        int row = h + j / 3 - 1, col = side * 32 + px + j % 3 - 1;
        float4 v = {0.f, 0.f, 0.f, 0.f};
        if ((unsigned)row < 64u && (unsigned)col < 64u)
          v = xb4[(row * 64 + col) * 64 + kb * 8 + q];
        unsigned p0 = (unsigned)f2bf(v.x) | ((unsigned)f2bf(v.y) << 16);
        unsigned p1 = (unsigned)f2bf(v.z) | ((unsigned)f2bf(v.w) << 16);
        *(uint2*)&sXo[px * XSTR + j * 32 + q * 4] = (uint2){p0, p1};
      }
    }
    __syncthreads();
#pragma unroll
    for (int ks = 0; ks < 9; ++ks) {
      if ((int)(ks >= 5) == kh) {
        int ksg = kb * 9 + ks;
        bf16x8 af =
            *(const bf16x8*)(wpmf + (size_t)ksg * 1024 + ot * 512 + lane * 8);
        bf16x8 bf = *(const bf16x8*)(bb + ks * 32);
        acc = __builtin_amdgcn_mfma_f32_16x16x32_bf16(af, bf, acc, 0, 0, 0);
      }
    }
  }
  __syncthreads();
  float* sR = (float*)sXo;
  if (kh == 1) {
    int base = (pxt * 2 + ot) * 256 + lane * 4;
#pragma unroll
    for (int r = 0; r < 4; ++r) sR[base + r] = acc[r];
  }
  __syncthreads();
  if (kh == 0) {
    int base = (pxt * 2 + ot) * 256 + lane * 4;
    int pxl = side * 32 + pxt * 16 + (lane & 15);
#pragma unroll
    for (int r = 0; r < 4; ++r) {
      int oc = ot * 16 + (lane >> 4) * 4 + r;
      if (oc < 27) {
        float v = acc[r] + sR[base + r];
        v += (oc < 18) ? b_p[oc] : b_m[oc - 18];
        if (oc >= 18) v = 1.f / (1.f + expf(-v));
        offm[((size_t)b * 27 + oc) * 4096 + h * 64 + pxl] = v;
      }
    }
  }
}

// ---------------------------------------------------------------------------
// K2: deformable gather (NHWC, float4-vectorized) + bf16 MFMA + BN partials.
// grid = 512 (XCD-swizzled, 2 blocks/CU), block = 512 (8 waves), 32 px.
// Staging unit = (k, px): 8 lanes x float4 (4 ch each), 4 taps per lane.
// MFMA: wave = 2 oc-tiles x 2 px-tiles (A-frag reused across px-tiles).
// ---------------------------------------------------------------------------
__global__ __launch_bounds__(512, 4) void k_deform(float* __restrict__ ws) {
  const float* offm = ws + WS_OFF;
  const float* xT = ws + WS_XT;
  const unsigned short* wfb = (const unsigned short*)(ws + WS_WF);
  float* y = ws + WS_Y;

  __shared__ __align__(16) uint4 sPK[288];
  __shared__ __align__(16) unsigned short sXu[32 * XSTR];

  int t = threadIdx.x, blk = blockIdx.x;
  int xcd = blk & 7, ii = blk >> 3;
  int b = xcd >> 1, h = (xcd & 1) * 32 + (ii >> 1), side = ii & 1;

  if (t < 288) {
    int k = t >> 5, w = side * 32 + (t & 31);
    size_t base = ((size_t)b * 27) * 4096 + h * 64 + w;
    float offx = offm[base + (size_t)k * 4096];
    float offy = offm[base + (size_t)(9 + k) * 4096];
    float mk   = offm[base + (size_t)(18 + k) * 4096];
    float pnx = (float)((k / 3 - 1) * 6);
    float pny = (float)((k % 3 - 1) * 6);
    float pxf = (float)(h + 1) + pnx + offx;
    float pyf = (float)(w + 1) + pny + offy;
    float fx = floorf(pxf), fy = floorf(pyf);
    float q0x = fminf(fmaxf(fx, 0.f), 75.f);
    float q1x = fminf(fmaxf(fx + 1.f, 0.f), 75.f);
    float q0y = fminf(fmaxf(fy, 0.f), 75.f);
    float q1y = fminf(fmaxf(fy + 1.f, 0.f), 75.f);
    float pxc = fminf(fmaxf(pxf, 0.f), 75.f);
    float pyc = fminf(fmaxf(pyf, 0.f), 75.f);
    float glt = (1.f + (q0x - pxc)) * (1.f + (q0y - pyc));
    float grb = (1.f - (q1x - pxc)) * (1.f - (q1y - pyc));
    float glb = (1.f + (q0x - pxc)) * (1.f - (q1y - pyc));
    float grt = (1.f - (q1x - pxc)) * (1.f + (q0y - pyc));
    int ix0 = (int)q0x - 6, ix1 = (int)q1x - 6;
    int iy0 = (int)q0y - 6, iy1 = (int)q1y - 6;
    bool v00 = (unsigned)ix0 < 64u && (unsigned)iy0 < 64u;
    bool v11 = (unsigned)ix1 < 64u && (unsigned)iy1 < 64u;
    bool v01 = (unsigned)ix0 < 64u && (unsigned)iy1 < 64u;
    bool v10 = (unsigned)ix1 < 64u && (unsigned)iy0 < 64u;
    unsigned a0 = v00 ? (unsigned)(ix0 * 64 + iy0) : 0u;
    unsigned a1 = v11 ? (unsigned)(ix1 * 64 + iy1) : 0u;
    unsigned a2 = v01 ? (unsigned)(ix0 * 64 + iy1) : 0u;
    unsigned a3 = v10 ? (unsigned)(ix1 * 64 + iy0) : 0u;
    float g0 = v00 ? glt * mk : 0.f;
    float g1 = v11 ? grb * mk : 0.f;
    float g2 = v01 ? glb * mk : 0.f;
    float g3 = v10 ? grt * mk : 0.f;
    uint4 pk;
    pk.x = a0 | (a1 << 16);
    pk.y = a2 | (a3 << 16);
    pk.z = (unsigned)f2bf(g0) | ((unsigned)f2bf(g1) << 16);
    pk.w = (unsigned)f2bf(g2) | ((unsigned)f2bf(g3) << 16);
    sPK[t] = pk;
  }

  int lane = t & 63, wv = __builtin_amdgcn_readfirstlane(t >> 6);
  f32x4 acc[2][2];  // [oc-tile][px-tile]
#pragma unroll
  for (int i = 0; i < 2; ++i)
#pragma unroll
    for (int jj = 0; jj < 2; ++jj) acc[i][jj] = (f32x4){0.f, 0.f, 0.f, 0.f};

  const float4* xb4 = (const float4*)(xT + (size_t)b * 1048576);
  const unsigned short* bb0 = &sXu[(lane & 15) * XSTR + (lane >> 4) * 8];
  const unsigned short* bb1 = bb0 + 16 * XSTR;
  int uq = t >> 3, q = t & 7;

  for (int kb = 0; kb < 8; ++kb) {
    __syncthreads();  // sXu free + (first iter) sPK visible
#pragma unroll
    for (int r = 0; r < 5; ++r) {
      int u = r * 64 + uq;
      if (u < 288) {
        uint4 pk = sPK[u];
        int k = u >> 5, px = u & 31;
        int cb = kb * 8 + q;
        float4 v0 = xb4[(int)(pk.x & 0xFFFFu) * 64 + cb];
        float4 v1 = xb4[(int)(pk.x >> 16) * 64 + cb];
        float4 v2 = xb4[(int)(pk.y & 0xFFFFu) * 64 + cb];
        float4 v3 = xb4[(int)(pk.y >> 16) * 64 + cb];
        float g0 = __uint_as_float((pk.z & 0xFFFFu) << 16);
        float g1 = __uint_as_float(pk.z & 0xFFFF0000u);
        float g2 = __uint_as_float((pk.w & 0xFFFFu) << 16);
        float g3 = __uint_as_float(pk.w & 0xFFFF0000u);
        float4 val;
        val.x = fmaf(g3, v3.x, fmaf(g2, v2.x, fmaf(g1, v1.x, g0 * v0.x)));
        val.y = fmaf(g3, v3.y, fmaf(g2, v2.y, fmaf(g1, v1.y, g0 * v0.y)));
        val.z = fmaf(g3, v3.z, fmaf(g2, v2.z, fmaf(g1, v1.z, g0 * v0.z)));
        val.w = fmaf(g3, v3.w, fmaf(g2, v2.w, fmaf(g1, v1.w, g0 * v0.w)));
        unsigned p0 = (unsigned)f2bf(val.x) | ((unsigned)f2bf(val.y) << 16);
        unsigned p1 = (unsigned)f2bf(val.z) | ((unsigned)f2bf(val.w) << 16);
        *(uint2*)&sXu[px * XSTR + k * 32 + q * 4] = (uint2){p0, p1};
      }
    }
    __syncthreads();
#pragma unroll
    for (int ks = 0; ks < 9; ++ks) {
      int ksg = kb * 9 + ks;
      const unsigned short* ap =
          wfb + (size_t)ksg * 8192 + (size_t)wv * 1024 + lane * 8;
      bf16x8 af0 = *(const bf16x8*)ap;
      bf16x8 af1 = *(const bf16x8*)(ap + 512);
      bf16x8 bf0 = *(const bf16x8*)(bb0 + ks * 32);
      bf16x8 bf1 = *(const bf16x8*)(bb1 + ks * 32);
      acc[0][0] = __builtin_amdgcn_mfma_f32_16x16x32_bf16(af0, bf0, acc[0][0], 0, 0, 0);
      acc[0][1] = __builtin_amdgcn_mfma_f32_16x16x32_bf16(af0, bf1, acc[0][1], 0, 0, 0);
      acc[1][0] = __builtin_amdgcn_mfma_f32_16x16x32_bf16(af1, bf0, acc[1][0], 0, 0, 0);
      acc[1][1] = __builtin_amdgcn_mfma_f32_16x16x32_bf16(af1, bf1, acc[1][1], 0, 0, 0);
    }
  }

  // epilogue: y stores + per-channel partials (16-lane xor-reduce over px)
  __syncthreads();  // sXu dead; reuse as reduce buffer
  float* sP = (float*)sXu;   // [256] sum
  float* sP2 = sP + 256;     // [256] sumsq
  int quad = lane >> 4, li = lane & 15;
  size_t ybase = ((size_t)b * PP) * 4096 + h * 64 + side * 32;
#pragma unroll
  for (int otl = 0; otl < 2; ++otl) {
#pragma unroll
    for (int r = 0; r < 4; ++r) {
      int oc = wv * 32 + otl * 16 + quad * 4 + r;
      float v0 = acc[otl][0][r];
      float v1 = acc[otl][1][r];
      float* yp = y + ybase + (size_t)oc * 4096 + li;
      yp[0] = v0;
      yp[16] = v1;
      float s = v0 + v1;
      float s2 = fmaf(v0, v0, v1 * v1);
      s += __shfl_xor(s, 1);  s2 += __shfl_xor(s2, 1);
      s += __shfl_xor(s, 2);  s2 += __shfl_xor(s2, 2);
      s += __shfl_xor(s, 4);  s2 += __shfl_xor(s2, 4);
      s += __shfl_xor(s, 8);  s2 += __shfl_xor(s2, 8);
      if (li == 0) {
        sP[oc] = s;
        sP2[oc] = s2;
      }
    }
  }
  __syncthreads();
  if (t < 256) {
    atomicAdd(&ws[WS_SUM + t], sP[t]);
    atomicAdd(&ws[WS_SUMSQ + t], sP2[t]);
  }
}

// ---------------------------------------------------------------------------
// K3: per-channel BN scale/shift.
// ---------------------------------------------------------------------------
__global__ void k_stats(float* __restrict__ ws, const float* __restrict__ gamma,
                        const float* __restrict__ beta) {
  int t = threadIdx.x;
  float s  = ws[WS_SUM + t];
  float s2 = ws[WS_SUMSQ + t];
  float mean = s * (1.f / 16384.f);
  float var  = fmaf(s2, 1.f / 16384.f, -mean * mean);
  float rstd = rsqrtf(var + 1e-5f);
  float sc = gamma[t] * rstd;
  ws[WS_SCALE + t] = sc;
  ws[WS_SHIFT + t] = fmaf(-mean, sc, beta[t]);
}

// ---------------------------------------------------------------------------
// K4: apply BN + ReLU, vectorized float4.
// ---------------------------------------------------------------------------
__global__ void k_bnrelu(const float* __restrict__ ws, float* __restrict__ out) {
  const float4* y4 = (const float4*)(ws + WS_Y);
  const float* scale = ws + WS_SCALE;
  const float* shift = ws + WS_SHIFT;
  float4* o4 = (float4*)out;
  const int n4 = 4 * PP * 1024;
  for (int i = blockIdx.x * blockDim.x + threadIdx.x; i < n4;
       i += gridDim.x * blockDim.x) {
    int oc = (i >> 10) & 255;
    float sc = scale[oc], sh = shift[oc];
    float4 v = y4[i];
    float4 r;
    r.x = fmaxf(fmaf(v.x, sc, sh), 0.f);
    r.y = fmaxf(fmaf(v.y, sc, sh), 0.f);
    r.z = fmaxf(fmaf(v.z, sc, sh), 0.f);
    r.w = fmaxf(fmaf(v.w, sc, sh), 0.f);
    o4[i] = r;
  }
}

extern "C" void kernel_launch(void* const* d_in, const int* in_sizes, int n_in,
                              void* d_out, int out_size, void* d_ws,
                              size_t ws_size, hipStream_t stream) {
  const float* x     = (const float*)d_in[0];
  const float* w_p   = (const float*)d_in[1];
  const float* b_p   = (const float*)d_in[2];
  const float* w_m   = (const float*)d_in[3];
  const float* b_m   = (const float*)d_in[4];
  const float* w     = (const float*)d_in[5];
  const float* gamma = (const float*)d_in[6];
  const float* beta  = (const float*)d_in[7];
  float* ws  = (float*)d_ws;
  float* out = (float*)d_out;

  k_prep<<<1664, 256, 0, stream>>>(x, w, w_p, w_m, ws);
  k_offmask<<<512, 512, 0, stream>>>(b_p, b_m, ws);
  k_deform<<<512, 512, 0, stream>>>(ws);
  k_stats<<<1, 256, 0, stream>>>(ws, gamma, beta);
  k_bnrelu<<<2048, 256, 0, stream>>>(ws, out);
}

// Round 6
// 167.851 us; speedup vs baseline: 2.2111x; 1.0108x over previous
//
#include <hip/hip_runtime.h>
#include <math.h>

// Problem constants (fixed by the reference setup_inputs)
#define CC 256
#define PP 256
#define XSTR 296  // LDS x_off row stride in ushort (288 K + 8 pad)

// Workspace layout (float element offsets)
#define WS_OFF   0ull        // [B][27][H][W]        = 442368
#define WS_Y     442368ull   // [B][P][H][W]         = 4194304
#define WS_SUM   4636672ull  // [256]
#define WS_SUMSQ 4636928ull  // [256]
#define WS_SCALE 4637184ull  // [256]
#define WS_SHIFT 4637440ull  // [256]
#define WS_XT    4637696ull  // NHWC x: [B][H][W][C] = 4194304 floats
#define WS_WF    8832000ull  // main W frags [ksg72][ot16][quad4][ocin16][j8] = 589824 us
#define WS_WPMF  9126912ull  // offs/mask W frags [ksg72][ot2][quad4][ocin16][j8] = 73728 us
// end: 9163776 floats = 36.7 MB

typedef __attribute__((ext_vector_type(8))) short bf16x8;
typedef __attribute__((ext_vector_type(4))) float f32x4;

static __device__ inline unsigned short f2bf(float f) {
  unsigned int u = __float_as_uint(f);
  unsigned int r = (u + 0x7FFFu + ((u >> 16) & 1u)) >> 16;
  return (unsigned short)r;
}

// ---------------------------------------------------------------------------
// K0: x NCHW -> NHWC transpose (blocks 0..1023) + weight fragment relayouts
// (blocks 1024..1663) + zero BN accumulators. Re-done every call.
// ---------------------------------------------------------------------------
__global__ __launch_bounds__(256) void k_prep(const float* __restrict__ x,
                                              const float* __restrict__ w,
                                              const float* __restrict__ w_p,
                                              const float* __restrict__ w_m,
                                              float* __restrict__ ws) {
  int blk = blockIdx.x, t = threadIdx.x;
  if (blk < 1024) {
    __shared__ float sT[64][65];
    int b = blk >> 8, h = (blk >> 2) & 63, c0 = (blk & 3) * 64;
    const float* xs = x + ((size_t)(b * 256 + c0) * 64 + h) * 64;
    int cl = t >> 6, wl = t & 63;
#pragma unroll
    for (int it = 0; it < 16; ++it) {
      int c = cl + it * 4;
      sT[c][wl] = xs[(size_t)c * 4096 + wl];
    }
    __syncthreads();
    float* xt = ws + WS_XT + ((size_t)b * 64 + h) * 16384 + c0;
    int c2 = t & 63, w2l = t >> 6;
#pragma unroll
    for (int it = 0; it < 16; ++it) {
      int w2 = w2l + it * 4;
      xt[(size_t)w2 * 256 + c2] = sT[c2][w2];
    }
  } else {
    int gid = (blk - 1024) * 256 + t;
    if (blk == 1024 && t < 512) ws[WS_SUM + t] = 0.f;  // SUM + SUMSQ
    unsigned short* wfb = (unsigned short*)(ws + WS_WF);
    for (int e = gid; e < 589824; e += 163840) {
      int j = e & 7, ocin = (e >> 3) & 15, quad = (e >> 7) & 3;
      int ot = (e >> 9) & 15, ksg = e >> 13;
      int kb = ksg / 9, ks = ksg - kb * 9;
      int c = kb * 32 + quad * 8 + j;
      int oc = ot * 16 + ocin;
      wfb[e] = f2bf(w[((size_t)oc * CC + c) * 9 + ks]);
    }
    unsigned short* wpmf = (unsigned short*)(ws + WS_WPMF);
    for (int e = gid; e < 73728; e += 163840) {
      int j = e & 7, ocin = (e >> 3) & 15, quad = (e >> 7) & 3;
      int ot = (e >> 9) & 1, ksg = e >> 10;
      int kb = ksg / 9, ks = ksg - kb * 9;
      int c = kb * 32 + quad * 8 + j;
      int oc = ot * 16 + ocin;
      float v = 0.f;
      if (oc < 18)      v = w_p[((size_t)oc * CC + c) * 9 + ks];
      else if (oc < 27) v = w_m[((size_t)(oc - 18) * CC + c) * 9 + ks];
      wpmf[e] = f2bf(v);
    }
  }
}

// ---------------------------------------------------------------------------
// K1: fused offset(18) + mask(9, sigmoid) 3x3 conv as im2col bf16 MFMA GEMM.
// grid = 512 (XCD-swizzled), block = 512 (8 waves), 32 px per block.
// Double-buffered LDS staging (1 barrier/K-tile); staging addresses hoisted
// to registers (kb-invariant). K split over wave-halves.
// ---------------------------------------------------------------------------
__global__ __launch_bounds__(512, 4) void k_offmask(const float* __restrict__ b_p,
                                                    const float* __restrict__ b_m,
                                                    float* __restrict__ ws) {
  const float* xT = ws + WS_XT;
  const unsigned short* wpmf = (const unsigned short*)(ws + WS_WPMF);
  float* offm = ws + WS_OFF;
  __shared__ __align__(16) unsigned short sXo0[32 * XSTR];
  __shared__ __align__(16) unsigned short sXo1[32 * XSTR];

  int t = threadIdx.x, blk = blockIdx.x;
  int xcd = blk & 7, ii = blk >> 3;
  int b = xcd >> 1, h = (xcd & 1) * 32 + (ii >> 1), side = ii & 1;

  int lane = t & 63, wv = __builtin_amdgcn_readfirstlane(t >> 6);
  int pxt = wv & 1, ot = (wv >> 1) & 1, kh = wv >> 2;
  f32x4 acc = {0.f, 0.f, 0.f, 0.f};
  const float4* xb4 = (const float4*)(xT + (size_t)b * 1048576);
  int uq = t >> 3, q = t & 7;

  // kb-invariant staging descriptors: 5 units/thread
  int oa[5], odst[5];
#pragma unroll
  for (int r = 0; r < 5; ++r) {
    int u = r * 64 + uq;
    if (u < 288) {
      int j = u >> 5, px = u & 31;
      int row = h + j / 3 - 1, col = side * 32 + px + j % 3 - 1;
      odst[r] = px * XSTR + j * 32 + q * 4;
      oa[r] = ((unsigned)row < 64u && (unsigned)col < 64u)
                  ? (row * 64 + col) * 64 + q : -1;
    } else {
      odst[r] = -1;
      oa[r] = -1;
    }
  }

  auto stage = [&](int kb, unsigned short* buf) {
    int cb = kb * 8;
#pragma unroll
    for (int r = 0; r < 5; ++r) {
      if (odst[r] >= 0) {
        float4 v = {0.f, 0.f, 0.f, 0.f};
        if (oa[r] >= 0) v = xb4[oa[r] + cb];
        unsigned p0 = (unsigned)f2bf(v.x) | ((unsigned)f2bf(v.y) << 16);
        unsigned p1 = (unsigned)f2bf(v.z) | ((unsigned)f2bf(v.w) << 16);
        *(uint2*)&buf[odst[r]] = (uint2){p0, p1};
      }
    }
  };

  stage(0, sXo0);
  __syncthreads();
  for (int kb = 0; kb < 8; ++kb) {
    unsigned short* cur = (kb & 1) ? sXo1 : sXo0;
    unsigned short* nxt = (kb & 1) ? sXo0 : sXo1;
    if (kb < 7) stage(kb + 1, nxt);
    const unsigned short* bb =
        &cur[(pxt * 16 + (lane & 15)) * XSTR + (lane >> 4) * 8];
#pragma unroll
    for (int ks = 0; ks < 9; ++ks) {
      if ((int)(ks >= 5) == kh) {
        int ksg = kb * 9 + ks;
        bf16x8 af =
            *(const bf16x8*)(wpmf + (size_t)ksg * 1024 + ot * 512 + lane * 8);
        bf16x8 bf = *(const bf16x8*)(bb + ks * 32);
        acc = __builtin_amdgcn_mfma_f32_16x16x32_bf16(af, bf, acc, 0, 0, 0);
      }
    }
    __syncthreads();
  }

  // cross-K-half reduce via LDS (buffer 0 is free: last MFMA read buffer 1)
  float* sR = (float*)sXo0;
  if (kh == 1) {
    int base = (pxt * 2 + ot) * 256 + lane * 4;
#pragma unroll
    for (int r = 0; r < 4; ++r) sR[base + r] = acc[r];
  }
  __syncthreads();
  if (kh == 0) {
    int base = (pxt * 2 + ot) * 256 + lane * 4;
    int pxl = side * 32 + pxt * 16 + (lane & 15);
#pragma unroll
    for (int r = 0; r < 4; ++r) {
      int oc = ot * 16 + (lane >> 4) * 4 + r;
      if (oc < 27) {
        float v = acc[r] + sR[base + r];
        v += (oc < 18) ? b_p[oc] : b_m[oc - 18];
        if (oc >= 18) v = 1.f / (1.f + expf(-v));
        offm[((size_t)b * 27 + oc) * 4096 + h * 64 + pxl] = v;
      }
    }
  }
}

// ---------------------------------------------------------------------------
// K2: deformable gather (NHWC, float4) + bf16 MFMA + BN partials.
// grid = 512 (XCD-swizzled, 2+ blocks/CU), block = 512 (8 waves), 32 px.
// Double-buffered LDS staging; tap addresses/weights preloaded to registers
// (kb-invariant). MFMA: wave = 2 oc-tiles x 2 px-tiles.
// ---------------------------------------------------------------------------
__global__ __launch_bounds__(512, 4) void k_deform(float* __restrict__ ws) {
  const float* offm = ws + WS_OFF;
  const float* xT = ws + WS_XT;
  const unsigned short* wfb = (const unsigned short*)(ws + WS_WF);
  float* y = ws + WS_Y;

  __shared__ __align__(16) uint4 sPK[288];
  __shared__ __align__(16) unsigned short sXu0[32 * XSTR];
  __shared__ __align__(16) unsigned short sXu1[32 * XSTR];

  int t = threadIdx.x, blk = blockIdx.x;
  int xcd = blk & 7, ii = blk >> 3;
  int b = xcd >> 1, h = (xcd & 1) * 32 + (ii >> 1), side = ii & 1;

  if (t < 288) {
    int k = t >> 5, w = side * 32 + (t & 31);
    size_t base = ((size_t)b * 27) * 4096 + h * 64 + w;
    float offx = offm[base + (size_t)k * 4096];
    float offy = offm[base + (size_t)(9 + k) * 4096];
    float mk   = offm[base + (size_t)(18 + k) * 4096];
    float pnx = (float)((k / 3 - 1) * 6);
    float pny = (float)((k % 3 - 1) * 6);
    float pxf = (float)(h + 1) + pnx + offx;
    float pyf = (float)(w + 1) + pny + offy;
    float fx = floorf(pxf), fy = floorf(pyf);
    float q0x = fminf(fmaxf(fx, 0.f), 75.f);
    float q1x = fminf(fmaxf(fx + 1.f, 0.f), 75.f);
    float q0y = fminf(fmaxf(fy, 0.f), 75.f);
    float q1y = fminf(fmaxf(fy + 1.f, 0.f), 75.f);
    float pxc = fminf(fmaxf(pxf, 0.f), 75.f);
    float pyc = fminf(fmaxf(pyf, 0.f), 75.f);
    float glt = (1.f + (q0x - pxc)) * (1.f + (q0y - pyc));
    float grb = (1.f - (q1x - pxc)) * (1.f - (q1y - pyc));
    float glb = (1.f + (q0x - pxc)) * (1.f - (q1y - pyc));
    float grt = (1.f - (q1x - pxc)) * (1.f + (q0y - pyc));
    int ix0 = (int)q0x - 6, ix1 = (int)q1x - 6;
    int iy0 = (int)q0y - 6, iy1 = (int)q1y - 6;
    bool v00 = (unsigned)ix0 < 64u && (unsigned)iy0 < 64u;
    bool v11 = (unsigned)ix1 < 64u && (unsigned)iy1 < 64u;
    bool v01 = (unsigned)ix0 < 64u && (unsigned)iy1 < 64u;
    bool v10 = (unsigned)ix1 < 64u && (unsigned)iy0 < 64u;
    unsigned a0 = v00 ? (unsigned)(ix0 * 64 + iy0) : 0u;
    unsigned a1 = v11 ? (unsigned)(ix1 * 64 + iy1) : 0u;
    unsigned a2 = v01 ? (unsigned)(ix0 * 64 + iy1) : 0u;
    unsigned a3 = v10 ? (unsigned)(ix1 * 64 + iy0) : 0u;
    float g0 = v00 ? glt * mk : 0.f;
    float g1 = v11 ? grb * mk : 0.f;
    float g2 = v01 ? glb * mk : 0.f;
    float g3 = v10 ? grt * mk : 0.f;
    uint4 pk;
    pk.x = a0 | (a1 << 16);
    pk.y = a2 | (a3 << 16);
    pk.z = (unsigned)f2bf(g0) | ((unsigned)f2bf(g1) << 16);
    pk.w = (unsigned)f2bf(g2) | ((unsigned)f2bf(g3) << 16);
    sPK[t] = pk;
  }
  __syncthreads();

  // preload kb-invariant staging descriptors: 5 units/thread
  int uq = t >> 3, q = t & 7;
  int ta0[5], ta1[5], ta2[5], ta3[5], tdst[5];
  float tg0[5], tg1[5], tg2[5], tg3[5];
#pragma unroll
  for (int r = 0; r < 5; ++r) {
    int u = r * 64 + uq;
    if (u < 288) {
      uint4 pk = sPK[u];
      int k = u >> 5, px = u & 31;
      ta0[r] = (int)(pk.x & 0xFFFFu) * 64 + q;
      ta1[r] = (int)(pk.x >> 16) * 64 + q;
      ta2[r] = (int)(pk.y & 0xFFFFu) * 64 + q;
      ta3[r] = (int)(pk.y >> 16) * 64 + q;
      tg0[r] = __uint_as_float((pk.z & 0xFFFFu) << 16);
      tg1[r] = __uint_as_float(pk.z & 0xFFFF0000u);
      tg2[r] = __uint_as_float((pk.w & 0xFFFFu) << 16);
      tg3[r] = __uint_as_float(pk.w & 0xFFFF0000u);
      tdst[r] = px * XSTR + k * 32 + q * 4;
    } else {
      tdst[r] = -1;
    }
  }

  int lane = t & 63, wv = __builtin_amdgcn_readfirstlane(t >> 6);
  f32x4 acc[2][2];  // [oc-tile][px-tile]
#pragma unroll
  for (int i = 0; i < 2; ++i)
#pragma unroll
    for (int jj = 0; jj < 2; ++jj) acc[i][jj] = (f32x4){0.f, 0.f, 0.f, 0.f};

  const float4* xb4 = (const float4*)(xT + (size_t)b * 1048576);

  auto stage = [&](int kb, unsigned short* buf) {
    int cb = kb * 8;
#pragma unroll
    for (int r = 0; r < 5; ++r) {
      if (tdst[r] >= 0) {
        float4 v0 = xb4[ta0[r] + cb];
        float4 v1 = xb4[ta1[r] + cb];
        float4 v2 = xb4[ta2[r] + cb];
        float4 v3 = xb4[ta3[r] + cb];
        float g0 = tg0[r], g1 = tg1[r], g2 = tg2[r], g3 = tg3[r];
        float4 val;
        val.x = fmaf(g3, v3.x, fmaf(g2, v2.x, fmaf(g1, v1.x, g0 * v0.x)));
        val.y = fmaf(g3, v3.y, fmaf(g2, v2.y, fmaf(g1, v1.y, g0 * v0.y)));
        val.z = fmaf(g3, v3.z, fmaf(g2, v2.z, fmaf(g1, v1.z, g0 * v0.z)));
        val.w = fmaf(g3, v3.w, fmaf(g2, v2.w, fmaf(g1, v1.w, g0 * v0.w)));
        unsigned p0 = (unsigned)f2bf(val.x) | ((unsigned)f2bf(val.y) << 16);
        unsigned p1 = (unsigned)f2bf(val.z) | ((unsigned)f2bf(val.w) << 16);
        *(uint2*)&buf[tdst[r]] = (uint2){p0, p1};
      }
    }
  };

  stage(0, sXu0);
  __syncthreads();
  for (int kb = 0; kb < 8; ++kb) {
    unsigned short* cur = (kb & 1) ? sXu1 : sXu0;
    unsigned short* nxt = (kb & 1) ? sXu0 : sXu1;
    if (kb < 7) stage(kb + 1, nxt);
    const unsigned short* bb0 = &cur[(lane & 15) * XSTR + (lane >> 4) * 8];
    const unsigned short* bb1 = bb0 + 16 * XSTR;
#pragma unroll
    for (int ks = 0; ks < 9; ++ks) {
      int ksg = kb * 9 + ks;
      const unsigned short* ap =
          wfb + (size_t)ksg * 8192 + (size_t)wv * 1024 + lane * 8;
      bf16x8 af0 = *(const bf16x8*)ap;
      bf16x8 af1 = *(const bf16x8*)(ap + 512);
      bf16x8 bf0 = *(const bf16x8*)(bb0 + ks * 32);
      bf16x8 bf1 = *(const bf16x8*)(bb1 + ks * 32);
      acc[0][0] = __builtin_amdgcn_mfma_f32_16x16x32_bf16(af0, bf0, acc[0][0], 0, 0, 0);
      acc[0][1] = __builtin_amdgcn_mfma_f32_16x16x32_bf16(af0, bf1, acc[0][1], 0, 0, 0);
      acc[1][0] = __builtin_amdgcn_mfma_f32_16x16x32_bf16(af1, bf0, acc[1][0], 0, 0, 0);
      acc[1][1] = __builtin_amdgcn_mfma_f32_16x16x32_bf16(af1, bf1, acc[1][1], 0, 0, 0);
    }
    __syncthreads();
  }

  // epilogue: y stores + per-channel partials (16-lane xor-reduce over px);
  // sPK is dead (descriptors preloaded) -> reuse as reduce buffer.
  float* sP = (float*)sPK;   // [256] sum
  float* sP2 = sP + 256;     // [256] sumsq
  int quad = lane >> 4, li = lane & 15;
  size_t ybase = ((size_t)b * PP) * 4096 + h * 64 + side * 32;
#pragma unroll
  for (int otl = 0; otl < 2; ++otl) {
#pragma unroll
    for (int r = 0; r < 4; ++r) {
      int oc = wv * 32 + otl * 16 + quad * 4 + r;
      float v0 = acc[otl][0][r];
      float v1 = acc[otl][1][r];
      float* yp = y + ybase + (size_t)oc * 4096 + li;
      yp[0] = v0;
      yp[16] = v1;
      float s = v0 + v1;
      float s2 = fmaf(v0, v0, v1 * v1);
      s += __shfl_xor(s, 1);  s2 += __shfl_xor(s2, 1);
      s += __shfl_xor(s, 2);  s2 += __shfl_xor(s2, 2);
      s += __shfl_xor(s, 4);  s2 += __shfl_xor(s2, 4);
      s += __shfl_xor(s, 8);  s2 += __shfl_xor(s2, 8);
      if (li == 0) {
        sP[oc] = s;
        sP2[oc] = s2;
      }
    }
  }
  __syncthreads();
  if (t < 256) {
    atomicAdd(&ws[WS_SUM + t], sP[t]);
    atomicAdd(&ws[WS_SUMSQ + t], sP2[t]);
  }
}

// ---------------------------------------------------------------------------
// K3: per-channel BN scale/shift.
// ---------------------------------------------------------------------------
__global__ void k_stats(float* __restrict__ ws, const float* __restrict__ gamma,
                        const float* __restrict__ beta) {
  int t = threadIdx.x;
  float s  = ws[WS_SUM + t];
  float s2 = ws[WS_SUMSQ + t];
  float mean = s * (1.f / 16384.f);
  float var  = fmaf(s2, 1.f / 16384.f, -mean * mean);
  float rstd = rsqrtf(var + 1e-5f);
  float sc = gamma[t] * rstd;
  ws[WS_SCALE + t] = sc;
  ws[WS_SHIFT + t] = fmaf(-mean, sc, beta[t]);
}

// ---------------------------------------------------------------------------
// K4: apply BN + ReLU, vectorized float4.
// ---------------------------------------------------------------------------
__global__ void k_bnrelu(const float* __restrict__ ws, float* __restrict__ out) {
  const float4* y4 = (const float4*)(ws + WS_Y);
  const float* scale = ws + WS_SCALE;
  const float* shift = ws + WS_SHIFT;
  float4* o4 = (float4*)out;
  const int n4 = 4 * PP * 1024;
  for (int i = blockIdx.x * blockDim.x + threadIdx.x; i < n4;
       i += gridDim.x * blockDim.x) {
    int oc = (i >> 10) & 255;
    float sc = scale[oc], sh = shift[oc];
    float4 v = y4[i];
    float4 r;
    r.x = fmaxf(fmaf(v.x, sc, sh), 0.f);
    r.y = fmaxf(fmaf(v.y, sc, sh), 0.f);
    r.z = fmaxf(fmaf(v.z, sc, sh), 0.f);
    r.w = fmaxf(fmaf(v.w, sc, sh), 0.f);
    o4[i] = r;
  }
}

extern "C" void kernel_launch(void* const* d_in, const int* in_sizes, int n_in,
                              void* d_out, int out_size, void* d_ws,
                              size_t ws_size, hipStream_t stream) {
  const float* x     = (const float*)d_in[0];
  const float* w_p   = (const float*)d_in[1];
  const float* b_p   = (const float*)d_in[2];
  const float* w_m   = (const float*)d_in[3];
  const float* b_m   = (const float*)d_in[4];
  const float* w     = (const float*)d_in[5];
  const float* gamma = (const float*)d_in[6];
  const float* beta  = (const float*)d_in[7];
  float* ws  = (float*)d_ws;
  float* out = (float*)d_out;

  k_prep<<<1664, 256, 0, stream>>>(x, w, w_p, w_m, ws);
  k_offmask<<<512, 512, 0, stream>>>(b_p, b_m, ws);
  k_deform<<<512, 512, 0, stream>>>(ws);
  k_stats<<<1, 256, 0, stream>>>(ws, gamma, beta);
  k_bnrelu<<<2048, 256, 0, stream>>>(ws, out);
}

// Round 7
// 159.031 us; speedup vs baseline: 2.3337x; 1.0555x over previous
//
#include <hip/hip_runtime.h>
#include <math.h>

// Problem constants (fixed by the reference setup_inputs)
#define CC 256
#define PP 256
#define XSTR 296  // LDS x_off row stride in ushort (288 K + 8 pad)

// Workspace layout (float element offsets)
#define WS_OFF   0ull        // [B][27][H][W]          = 442368
#define WS_Y     442368ull   // [B][P][H][W]           = 4194304
#define WS_SUM   4636672ull  // [256]
#define WS_SUMSQ 4636928ull  // [256]
#define WS_SCALE 4637184ull  // [256]
#define WS_SHIFT 4637440ull  // [256]
#define WS_XT    4637696ull  // NHWC x, bf16: [B][H][W][C] = 4194304 ushort
#define WS_WF    6734848ull  // main W frags [ksg72][ot16][quad4][ocin16][j8] = 589824 us
#define WS_WPMF  7029760ull  // offs/mask W frags [ksg72][ot2][quad4][ocin16][j8] = 73728 us
// end: 7066624 floats = 28.3 MB

typedef __attribute__((ext_vector_type(8))) short bf16x8;
typedef __attribute__((ext_vector_type(4))) float f32x4;

static __device__ inline unsigned short f2bf(float f) {
  unsigned int u = __float_as_uint(f);
  unsigned int r = (u + 0x7FFFu + ((u >> 16) & 1u)) >> 16;
  return (unsigned short)r;
}
static __device__ inline float bf2f(short s) {
  return __uint_as_float(((unsigned)(unsigned short)s) << 16);
}

// ---------------------------------------------------------------------------
// K0: x NCHW -> NHWC bf16 transpose (blocks 0..1023) + weight fragment
// relayouts (blocks 1024..1663) + zero BN accumulators.
// ---------------------------------------------------------------------------
__global__ __launch_bounds__(256) void k_prep(const float* __restrict__ x,
                                              const float* __restrict__ w,
                                              const float* __restrict__ w_p,
                                              const float* __restrict__ w_m,
                                              float* __restrict__ ws) {
  int blk = blockIdx.x, t = threadIdx.x;
  if (blk < 1024) {
    __shared__ float sT[64][65];
    int b = blk >> 8, h = (blk >> 2) & 63, c0 = (blk & 3) * 64;
    const float* xs = x + ((size_t)(b * 256 + c0) * 64 + h) * 64;
    int cl = t >> 6, wl = t & 63;
#pragma unroll
    for (int it = 0; it < 16; ++it) {
      int c = cl + it * 4;
      sT[c][wl] = xs[(size_t)c * 4096 + wl];
    }
    __syncthreads();
    unsigned short* xt = (unsigned short*)(ws + WS_XT) +
                         ((size_t)b * 64 + h) * 16384 + c0;
    int c2 = t & 63, w2l = t >> 6;
#pragma unroll
    for (int it = 0; it < 16; ++it) {
      int w2 = w2l + it * 4;
      xt[(size_t)w2 * 256 + c2] = f2bf(sT[c2][w2]);
    }
  } else {
    int gid = (blk - 1024) * 256 + t;
    if (blk == 1024 && t < 512) ws[WS_SUM + t] = 0.f;  // SUM + SUMSQ
    unsigned short* wfb = (unsigned short*)(ws + WS_WF);
    for (int e = gid; e < 589824; e += 163840) {
      int j = e & 7, ocin = (e >> 3) & 15, quad = (e >> 7) & 3;
      int ot = (e >> 9) & 15, ksg = e >> 13;
      int kb = ksg / 9, ks = ksg - kb * 9;
      int c = kb * 32 + quad * 8 + j;
      int oc = ot * 16 + ocin;
      wfb[e] = f2bf(w[((size_t)oc * CC + c) * 9 + ks]);
    }
    unsigned short* wpmf = (unsigned short*)(ws + WS_WPMF);
    for (int e = gid; e < 73728; e += 163840) {
      int j = e & 7, ocin = (e >> 3) & 15, quad = (e >> 7) & 3;
      int ot = (e >> 9) & 1, ksg = e >> 10;
      int kb = ksg / 9, ks = ksg - kb * 9;
      int c = kb * 32 + quad * 8 + j;
      int oc = ot * 16 + ocin;
      float v = 0.f;
      if (oc < 18)      v = w_p[((size_t)oc * CC + c) * 9 + ks];
      else if (oc < 27) v = w_m[((size_t)(oc - 18) * CC + c) * 9 + ks];
      wpmf[e] = f2bf(v);
    }
  }
}

// ---------------------------------------------------------------------------
// K1: fused offset(18) + mask(9, sigmoid) 3x3 conv as im2col bf16 MFMA GEMM.
// grid = 512, block = 512 (8 waves), 32 px. bf16 xT: one b128 load = 8 ch.
// Staging unit = 4 lanes (32 ch); double-buffered LDS; K over wave-halves.
// ---------------------------------------------------------------------------
__global__ __launch_bounds__(512, 4) void k_offmask(const float* __restrict__ b_p,
                                                    const float* __restrict__ b_m,
                                                    float* __restrict__ ws) {
  const unsigned short* xT = (const unsigned short*)(ws + WS_XT);
  const unsigned short* wpmf = (const unsigned short*)(ws + WS_WPMF);
  float* offm = ws + WS_OFF;
  __shared__ __align__(16) unsigned short sXo0[32 * XSTR];
  __shared__ __align__(16) unsigned short sXo1[32 * XSTR];

  int t = threadIdx.x, blk = blockIdx.x;
  int xcd = blk & 7, ii = blk >> 3;
  int b = xcd >> 1, h = (xcd & 1) * 32 + (ii >> 1), side = ii & 1;

  int lane = t & 63, wv = __builtin_amdgcn_readfirstlane(t >> 6);
  int pxt = wv & 1, ot = (wv >> 1) & 1, kh = wv >> 2;
  f32x4 acc = {0.f, 0.f, 0.f, 0.f};
  const unsigned short* xb = xT + (size_t)b * 1048576;
  int q = t & 3, uq = t >> 2;

  // kb-invariant staging descriptors: 3 units/thread (4-lane units)
  int oa[3], odst[3];
#pragma unroll
  for (int r = 0; r < 3; ++r) {
    int u = r * 128 + uq;
    odst[r] = -1;
    oa[r] = -1;
    if (u < 288) {
      int j = u >> 5, px = u & 31;
      int row = h + j / 3 - 1, col = side * 32 + px + j % 3 - 1;
      odst[r] = px * XSTR + j * 32 + q * 8;
      if ((unsigned)row < 64u && (unsigned)col < 64u)
        oa[r] = (row * 64 + col) * 256 + q * 8;
    }
  }

  auto stage = [&](int kb, unsigned short* buf) {
    int cb = kb * 32;
#pragma unroll
    for (int r = 0; r < 3; ++r) {
      if (odst[r] >= 0) {
        bf16x8 v = {0, 0, 0, 0, 0, 0, 0, 0};
        if (oa[r] >= 0) v = *(const bf16x8*)(xb + oa[r] + cb);
        *(bf16x8*)&buf[odst[r]] = v;
      }
    }
  };

  stage(0, sXo0);
  __syncthreads();
  for (int kb = 0; kb < 8; ++kb) {
    unsigned short* cur = (kb & 1) ? sXo1 : sXo0;
    unsigned short* nxt = (kb & 1) ? sXo0 : sXo1;
    if (kb < 7) stage(kb + 1, nxt);
    const unsigned short* bb =
        &cur[(pxt * 16 + (lane & 15)) * XSTR + (lane >> 4) * 8];
#pragma unroll
    for (int ks = 0; ks < 9; ++ks) {
      if ((int)(ks >= 5) == kh) {
        int ksg = kb * 9 + ks;
        bf16x8 af =
            *(const bf16x8*)(wpmf + (size_t)ksg * 1024 + ot * 512 + lane * 8);
        bf16x8 bf = *(const bf16x8*)(bb + ks * 32);
        acc = __builtin_amdgcn_mfma_f32_16x16x32_bf16(af, bf, acc, 0, 0, 0);
      }
    }
    __syncthreads();
  }

  // cross-K-half reduce via LDS (buffer 0 free: last MFMA read buffer 1)
  float* sR = (float*)sXo0;
  if (kh == 1) {
    int base = (pxt * 2 + ot) * 256 + lane * 4;
#pragma unroll
    for (int r = 0; r < 4; ++r) sR[base + r] = acc[r];
  }
  __syncthreads();
  if (kh == 0) {
    int base = (pxt * 2 + ot) * 256 + lane * 4;
    int pxl = side * 32 + pxt * 16 + (lane & 15);
#pragma unroll
    for (int r = 0; r < 4; ++r) {
      int oc = ot * 16 + (lane >> 4) * 4 + r;
      if (oc < 27) {
        float v = acc[r] + sR[base + r];
        v += (oc < 18) ? b_p[oc] : b_m[oc - 18];
        if (oc >= 18) v = 1.f / (1.f + expf(-v));
        offm[((size_t)b * 27 + oc) * 4096 + h * 64 + pxl] = v;
      }
    }
  }
}

// ---------------------------------------------------------------------------
// K2: deformable gather (NHWC bf16) + bf16 MFMA + BN partials.
// grid = 512, block = 512 (8 waves), 32 px. Staging unit = 4 lanes: each lane
// loads 4 taps x 8ch (b128), blends in fp32, stores one b128. Descriptors
// computed per-thread (no sPK). Double-buffered LDS.
// ---------------------------------------------------------------------------
__global__ __launch_bounds__(512, 4) void k_deform(float* __restrict__ ws) {
  const float* offm = ws + WS_OFF;
  const unsigned short* xT = (const unsigned short*)(ws + WS_XT);
  const unsigned short* wfb = (const unsigned short*)(ws + WS_WF);
  float* y = ws + WS_Y;

  __shared__ __align__(16) unsigned short sXu0[32 * XSTR];
  __shared__ __align__(16) unsigned short sXu1[32 * XSTR];

  int t = threadIdx.x, blk = blockIdx.x;
  int xcd = blk & 7, ii = blk >> 3;
  int b = xcd >> 1, h = (xcd & 1) * 32 + (ii >> 1), side = ii & 1;

  int q = t & 3, uq = t >> 2;
  int ta0[3], ta1[3], ta2[3], ta3[3], tdst[3];
  float tg0[3], tg1[3], tg2[3], tg3[3];
#pragma unroll
  for (int r = 0; r < 3; ++r) {
    int u = r * 128 + uq;
    tdst[r] = -1;
    if (u < 288) {
      int k = u >> 5, px = u & 31;
      int w = side * 32 + px;
      size_t base = ((size_t)b * 27) * 4096 + h * 64 + w;
      float offx = offm[base + (size_t)k * 4096];
      float offy = offm[base + (size_t)(9 + k) * 4096];
      float mk   = offm[base + (size_t)(18 + k) * 4096];
      float pnx = (float)((k / 3 - 1) * 6);
      float pny = (float)((k % 3 - 1) * 6);
      float pxf = (float)(h + 1) + pnx + offx;
      float pyf = (float)(w + 1) + pny + offy;
      float fx = floorf(pxf), fy = floorf(pyf);
      float q0x = fminf(fmaxf(fx, 0.f), 75.f);
      float q1x = fminf(fmaxf(fx + 1.f, 0.f), 75.f);
      float q0y = fminf(fmaxf(fy, 0.f), 75.f);
      float q1y = fminf(fmaxf(fy + 1.f, 0.f), 75.f);
      float pxc = fminf(fmaxf(pxf, 0.f), 75.f);
      float pyc = fminf(fmaxf(pyf, 0.f), 75.f);
      float glt = (1.f + (q0x - pxc)) * (1.f + (q0y - pyc));
      float grb = (1.f - (q1x - pxc)) * (1.f - (q1y - pyc));
      float glb = (1.f + (q0x - pxc)) * (1.f - (q1y - pyc));
      float grt = (1.f - (q1x - pxc)) * (1.f + (q0y - pyc));
      int ix0 = (int)q0x - 6, ix1 = (int)q1x - 6;
      int iy0 = (int)q0y - 6, iy1 = (int)q1y - 6;
      bool v00 = (unsigned)ix0 < 64u && (unsigned)iy0 < 64u;
      bool v11 = (unsigned)ix1 < 64u && (unsigned)iy1 < 64u;
      bool v01 = (unsigned)ix0 < 64u && (unsigned)iy1 < 64u;
      bool v10 = (unsigned)ix1 < 64u && (unsigned)iy0 < 64u;
      ta0[r] = (v00 ? (ix0 * 64 + iy0) : 0) * 256 + q * 8;
      ta1[r] = (v11 ? (ix1 * 64 + iy1) : 0) * 256 + q * 8;
      ta2[r] = (v01 ? (ix0 * 64 + iy1) : 0) * 256 + q * 8;
      ta3[r] = (v10 ? (ix1 * 64 + iy0) : 0) * 256 + q * 8;
      tg0[r] = v00 ? glt * mk : 0.f;
      tg1[r] = v11 ? grb * mk : 0.f;
      tg2[r] = v01 ? glb * mk : 0.f;
      tg3[r] = v10 ? grt * mk : 0.f;
      tdst[r] = px * XSTR + k * 32 + q * 8;
    }
  }

  int lane = t & 63, wv = __builtin_amdgcn_readfirstlane(t >> 6);
  f32x4 acc[2][2];  // [oc-tile][px-tile]
#pragma unroll
  for (int i = 0; i < 2; ++i)
#pragma unroll
    for (int jj = 0; jj < 2; ++jj) acc[i][jj] = (f32x4){0.f, 0.f, 0.f, 0.f};

  const unsigned short* xb = xT + (size_t)b * 1048576;

  auto stage = [&](int kb, unsigned short* buf) {
    int cb = kb * 32;
#pragma unroll
    for (int r = 0; r < 3; ++r) {
      if (tdst[r] >= 0) {
        bf16x8 t0 = *(const bf16x8*)(xb + ta0[r] + cb);
        bf16x8 t1 = *(const bf16x8*)(xb + ta1[r] + cb);
        bf16x8 t2 = *(const bf16x8*)(xb + ta2[r] + cb);
        bf16x8 t3 = *(const bf16x8*)(xb + ta3[r] + cb);
        float g0 = tg0[r], g1 = tg1[r], g2 = tg2[r], g3 = tg3[r];
        unsigned short pk[8];
#pragma unroll
        for (int i = 0; i < 8; ++i) {
          float val = g0 * bf2f(t0[i]);
          val = fmaf(g1, bf2f(t1[i]), val);
          val = fmaf(g2, bf2f(t2[i]), val);
          val = fmaf(g3, bf2f(t3[i]), val);
          pk[i] = f2bf(val);
        }
        uint4 w4;
        w4.x = (unsigned)pk[0] | ((unsigned)pk[1] << 16);
        w4.y = (unsigned)pk[2] | ((unsigned)pk[3] << 16);
        w4.z = (unsigned)pk[4] | ((unsigned)pk[5] << 16);
        w4.w = (unsigned)pk[6] | ((unsigned)pk[7] << 16);
        *(uint4*)&buf[tdst[r]] = w4;
      }
    }
  };

  stage(0, sXu0);
  __syncthreads();
  for (int kb = 0; kb < 8; ++kb) {
    unsigned short* cur = (kb & 1) ? sXu1 : sXu0;
    unsigned short* nxt = (kb & 1) ? sXu0 : sXu1;
    if (kb < 7) stage(kb + 1, nxt);
    const unsigned short* bb0 = &cur[(lane & 15) * XSTR + (lane >> 4) * 8];
    const unsigned short* bb1 = bb0 + 16 * XSTR;
#pragma unroll
    for (int ks = 0; ks < 9; ++ks) {
      int ksg = kb * 9 + ks;
      const unsigned short* ap =
          wfb + (size_t)ksg * 8192 + (size_t)wv * 1024 + lane * 8;
      bf16x8 af0 = *(const bf16x8*)ap;
      bf16x8 af1 = *(const bf16x8*)(ap + 512);
      bf16x8 bf0 = *(const bf16x8*)(bb0 + ks * 32);
      bf16x8 bf1 = *(const bf16x8*)(bb1 + ks * 32);
      acc[0][0] = __builtin_amdgcn_mfma_f32_16x16x32_bf16(af0, bf0, acc[0][0], 0, 0, 0);
      acc[0][1] = __builtin_amdgcn_mfma_f32_16x16x32_bf16(af0, bf1, acc[0][1], 0, 0, 0);
      acc[1][0] = __builtin_amdgcn_mfma_f32_16x16x32_bf16(af1, bf0, acc[1][0], 0, 0, 0);
      acc[1][1] = __builtin_amdgcn_mfma_f32_16x16x32_bf16(af1, bf1, acc[1][1], 0, 0, 0);
    }
    __syncthreads();
  }

  // epilogue: y stores + per-channel partials (16-lane xor-reduce over px);
  // sXu0 free (last MFMA read sXu1).
  float* sP = (float*)sXu0;  // [256] sum
  float* sP2 = sP + 256;     // [256] sumsq
  int quad = lane >> 4, li = lane & 15;
  size_t ybase = ((size_t)b * PP) * 4096 + h * 64 + side * 32;
#pragma unroll
  for (int otl = 0; otl < 2; ++otl) {
#pragma unroll
    for (int r = 0; r < 4; ++r) {
      int oc = wv * 32 + otl * 16 + quad * 4 + r;
      float v0 = acc[otl][0][r];
      float v1 = acc[otl][1][r];
      float* yp = y + ybase + (size_t)oc * 4096 + li;
      yp[0] = v0;
      yp[16] = v1;
      float s = v0 + v1;
      float s2 = fmaf(v0, v0, v1 * v1);
      s += __shfl_xor(s, 1);  s2 += __shfl_xor(s2, 1);
      s += __shfl_xor(s, 2);  s2 += __shfl_xor(s2, 2);
      s += __shfl_xor(s, 4);  s2 += __shfl_xor(s2, 4);
      s += __shfl_xor(s, 8);  s2 += __shfl_xor(s2, 8);
      if (li == 0) {
        sP[oc] = s;
        sP2[oc] = s2;
      }
    }
  }
  __syncthreads();
  if (t < 256) {
    atomicAdd(&ws[WS_SUM + t], sP[t]);
    atomicAdd(&ws[WS_SUMSQ + t], sP2[t]);
  }
}

// ---------------------------------------------------------------------------
// K3: per-channel BN scale/shift.
// ---------------------------------------------------------------------------
__global__ void k_stats(float* __restrict__ ws, const float* __restrict__ gamma,
                        const float* __restrict__ beta) {
  int t = threadIdx.x;
  float s  = ws[WS_SUM + t];
  float s2 = ws[WS_SUMSQ + t];
  float mean = s * (1.f / 16384.f);
  float var  = fmaf(s2, 1.f / 16384.f, -mean * mean);
  float rstd = rsqrtf(var + 1e-5f);
  float sc = gamma[t] * rstd;
  ws[WS_SCALE + t] = sc;
  ws[WS_SHIFT + t] = fmaf(-mean, sc, beta[t]);
}

// ---------------------------------------------------------------------------
// K4: apply BN + ReLU, vectorized float4.
// ---------------------------------------------------------------------------
__global__ void k_bnrelu(const float* __restrict__ ws, float* __restrict__ out) {
  const float4* y4 = (const float4*)(ws + WS_Y);
  const float* scale = ws + WS_SCALE;
  const float* shift = ws + WS_SHIFT;
  float4* o4 = (float4*)out;
  const int n4 = 4 * PP * 1024;
  for (int i = blockIdx.x * blockDim.x + threadIdx.x; i < n4;
       i += gridDim.x * blockDim.x) {
    int oc = (i >> 10) & 255;
    float sc = scale[oc], sh = shift[oc];
    float4 v = y4[i];
    float4 r;
    r.x = fmaxf(fmaf(v.x, sc, sh), 0.f);
    r.y = fmaxf(fmaf(v.y, sc, sh), 0.f);
    r.z = fmaxf(fmaf(v.z, sc, sh), 0.f);
    r.w = fmaxf(fmaf(v.w, sc, sh), 0.f);
    o4[i] = r;
  }
}

extern "C" void kernel_launch(void* const* d_in, const int* in_sizes, int n_in,
                              void* d_out, int out_size, void* d_ws,
                              size_t ws_size, hipStream_t stream) {
  const float* x     = (const float*)d_in[0];
  const float* w_p   = (const float*)d_in[1];
  const float* b_p   = (const float*)d_in[2];
  const float* w_m   = (const float*)d_in[3];
  const float* b_m   = (const float*)d_in[4];
  const float* w     = (const float*)d_in[5];
  const float* gamma = (const float*)d_in[6];
  const float* beta  = (const float*)d_in[7];
  float* ws  = (float*)d_ws;
  float* out = (float*)d_out;

  k_prep<<<1664, 256, 0, stream>>>(x, w, w_p, w_m, ws);
  k_offmask<<<512, 512, 0, stream>>>(b_p, b_m, ws);
  k_deform<<<512, 512, 0, stream>>>(ws);
  k_stats<<<1, 256, 0, stream>>>(ws, gamma, beta);
  k_bnrelu<<<2048, 256, 0, stream>>>(ws, out);
}